// Round 14
// baseline (96.300 us; speedup 1.0000x reference)
//
#include <hip/hip_runtime.h>

// GCN 2-layer: out = Ahat * relu(Ahat*(X W1)+b1) * W2 + b2
// Ahat = D^-1/2 (A+I) D^-1/2, pull-based CSR aggregation.
// R21: degree-sorted perm for k_agg1. Its j0-loop runs at the GROUP-MAX
//     degree: 8 iid Poisson(16) degrees -> cm ~ 22-25 vs mean 16, i.e.
//     30-40% masked gather iterations per wave. k_bucket now counting-sorts
//     its 256 nodes by degree (64-bin, 2 phases, reuses in-LDS degrees)
//     into perm[]; agg1 indirects n = perm[slot] so groups have near-equal
//     degrees and cm ~ cnt. Base = R20 (88.6us best) otherwise unchanged.

#define D_IN 64
#define NBBITS 8           // 256 nodes per bucket
#define NBK_PAD 512        // padded bucket count (N=100K -> 391 real)
#define BSTRIDE 16         // bptr stride: one counter per 64-B cache line
#define PCH 4096           // edges per part block
#define NWV 8              // waves per part block
#define SCAP 5120          // per-bucket edge capacity (mean ~4092, sd ~64)
#define RPB 10             // k_bucket register entries per thread (512*10=5120)

typedef __attribute__((ext_vector_type(8))) short bf16x8;
typedef __attribute__((ext_vector_type(4))) float f32x4;

// ---- bf16 helpers (RN-even) ----
__device__ __forceinline__ float b2f(unsigned short u) {
    unsigned v = ((unsigned)u) << 16;
    float f;
    __builtin_memcpy(&f, &v, 4);
    return f;
}
__device__ __forceinline__ unsigned short f2b(float f) {
    unsigned u;
    __builtin_memcpy(&u, &f, 4);
    u += 0x7FFFu + ((u >> 16) & 1u);
    return (unsigned short)(u >> 16);
}

// accumulate 8 bf16 features (one uint4) scaled by wgt into a[0..7]
__device__ __forceinline__ void acc8(float* a, uint4 rv, float wgt) {
    a[0] = fmaf(wgt, b2f((unsigned short)(rv.x & 0xFFFFu)), a[0]);
    a[1] = fmaf(wgt, b2f((unsigned short)(rv.x >> 16)), a[1]);
    a[2] = fmaf(wgt, b2f((unsigned short)(rv.y & 0xFFFFu)), a[2]);
    a[3] = fmaf(wgt, b2f((unsigned short)(rv.y >> 16)), a[3]);
    a[4] = fmaf(wgt, b2f((unsigned short)(rv.z & 0xFFFFu)), a[4]);
    a[5] = fmaf(wgt, b2f((unsigned short)(rv.z >> 16)), a[5]);
    a[6] = fmaf(wgt, b2f((unsigned short)(rv.w & 0xFFFFu)), a[6]);
    a[7] = fmaf(wgt, b2f((unsigned short)(rv.w >> 16)), a[7]);
}

// Fat kernel: blocks [0, nPart) partition 4096-edge chunks (counting sort
// with per-wave split histograms, 512 buckets, edge-major dense flush);
// blocks [nPart, grid) do H1 = bf16(X @ W1) via MFMA 16x16x32 bf16.
__global__ __launch_bounds__(512, 8) void k_part_gemm(
        const int* __restrict__ ep, int* __restrict__ bptr,
        unsigned* __restrict__ ebuf,
        const float* __restrict__ x, const float* __restrict__ W,
        unsigned short* __restrict__ H, int E, int N, int nPart, int nGemm) {
    __shared__ __align__(16) char smraw[39040];
    int tid = threadIdx.x;
    int lane = tid & 63;
    int wv = tid >> 6;                            // wave 0..7

    if (blockIdx.x < nPart) {
        // ---------------- partition path ----------------
        int* whist = (int*)smraw;                 // [8][512] per-wave hists
        int* lofs  = whist + NWV * NBK_PAD;       // [512]
        int* hcnt  = lofs + NBK_PAD;              // [512]
        int* gbase = hcnt + NBK_PAD;              // [512]
        int* fsh   = gbase + NBK_PAD;             // [16]: flag + 8 wave sums
        unsigned* stage = (unsigned*)(fsh + 16);  // [PCH]

        for (int i = tid; i < NWV * NBK_PAD; i += 512) whist[i] = 0;
        // per-block dtype detect (8 KB redundant read, L2-shared)
        if (tid < 64) {
            int bad = 0;
            for (int i = tid; i < 1024; i += 64)
                if (ep[2 * i + 1] != 0) bad = 1;
            unsigned long long m = __ballot(bad);
            if (tid == 0) fsh[0] = (m == 0ull) ? 1 : 0;   // 1 => int64
        }
        __syncthreads();
        int f = fsh[0];
        long base = (long)blockIdx.x * PCH;
        long rem64 = (long)E - base;
        int nE = rem64 > PCH ? PCH : (int)rem64;
        int j0 = tid * 8;                 // this thread's 8 local edges
        int nv = nE - j0;
        nv = nv < 0 ? 0 : (nv > 8 ? 8 : nv);
        unsigned cc[8], rr2[8];
        #pragma unroll
        for (int k = 0; k < 8; ++k) { cc[k] = 0; rr2[k] = 0; }
        bool fullv = (nv == 8);
        const uint4* p4 = (const uint4*)ep;
        // ---- load 8 cols into registers (coalesced uint4 when aligned) ----
        if (f) {
            if (fullv && ((E & 1) == 0)) {
                size_t cb = ((size_t)E + (size_t)base + j0) >> 1;   // uint4 idx
                uint4 a0 = p4[cb + 0], a1 = p4[cb + 1];
                uint4 a2 = p4[cb + 2], a3 = p4[cb + 3];
                cc[0] = a0.x; cc[1] = a0.z; cc[2] = a1.x; cc[3] = a1.z;
                cc[4] = a2.x; cc[5] = a2.z; cc[6] = a3.x; cc[7] = a3.z;
            } else {
                for (int k = 0; k < 8; ++k)
                    if (k < nv) cc[k] = (unsigned)ep[2 * ((size_t)E + base + j0 + k)];
            }
        } else {
            if (fullv && ((E & 3) == 0)) {
                size_t cb = ((size_t)E + (size_t)base + j0) >> 2;
                uint4 a0 = p4[cb + 0], a1 = p4[cb + 1];
                cc[0] = a0.x; cc[1] = a0.y; cc[2] = a0.z; cc[3] = a0.w;
                cc[4] = a1.x; cc[5] = a1.y; cc[6] = a1.z; cc[7] = a1.w;
            } else {
                for (int k = 0; k < 8; ++k)
                    if (k < nv) cc[k] = (unsigned)ep[(size_t)E + base + j0 + k];
            }
        }
        // ---- row loads issued BEFORE hist: cols+rows in flight together ----
        if (f) {
            if (fullv && ((E & 1) == 0)) {
                size_t rbb = ((size_t)base + j0) >> 1;
                uint4 b0 = p4[rbb + 0], b1 = p4[rbb + 1];
                uint4 b2 = p4[rbb + 2], b3 = p4[rbb + 3];
                rr2[0] = b0.x; rr2[1] = b0.z; rr2[2] = b1.x; rr2[3] = b1.z;
                rr2[4] = b2.x; rr2[5] = b2.z; rr2[6] = b3.x; rr2[7] = b3.z;
            } else {
                for (int k = 0; k < 8; ++k)
                    if (k < nv) rr2[k] = (unsigned)ep[2 * ((size_t)base + j0 + k)];
            }
        } else {
            if (fullv && ((E & 3) == 0)) {
                size_t rbb = ((size_t)base + j0) >> 2;
                uint4 b0 = p4[rbb + 0], b1 = p4[rbb + 1];
                rr2[0] = b0.x; rr2[1] = b0.y; rr2[2] = b0.z; rr2[3] = b0.w;
                rr2[4] = b1.x; rr2[5] = b1.y; rr2[6] = b1.z; rr2[7] = b1.w;
            } else {
                for (int k = 0; k < 8; ++k)
                    if (k < nv) rr2[k] = (unsigned)ep[(size_t)base + j0 + k];
            }
        }
        // per-wave histogram (collisions only intra-wave)
        int* myh = whist + wv * NBK_PAD;
        #pragma unroll
        for (int k = 0; k < 8; ++k)
            if (k < nv) atomicAdd(&myh[cc[k] >> NBBITS], 1);
        __syncthreads();
        // ---- combine per-wave hists + 512-entry exclusive scan ----
        if (tid < NBK_PAD) {
            int run = 0;
            #pragma unroll
            for (int w = 0; w < NWV; ++w) {
                int v = whist[w * NBK_PAD + tid];
                whist[w * NBK_PAD + tid] = run;   // per-wave prefix in bucket
                run += v;
            }
            hcnt[tid] = run;
            int s = run;
            #pragma unroll
            for (int off = 1; off < 64; off <<= 1) {
                int t2 = __shfl(s, lane - off);
                if (lane >= off) s += t2;
            }
            if (lane == 63) fsh[1 + (tid >> 6)] = s;
            lofs[tid] = s - run;
        }
        __syncthreads();
        if (tid < NBK_PAD) {
            int w8 = tid >> 6, add = 0;
            #pragma unroll
            for (int q = 0; q < NWV; ++q)
                if (q < w8) add += fsh[1 + q];
            lofs[tid] += add;
        }
        __syncthreads();
        // fold bucket base into per-wave cursors
        for (int i = tid; i < NWV * NBK_PAD; i += 512)
            whist[i] += lofs[i & (NBK_PAD - 1)];
        __syncthreads();
        // ---- scatter into LDS stage (cursor atomics intra-wave only) ----
        #pragma unroll
        for (int k = 0; k < 8; ++k) {
            if (k < nv) {
                unsigned c = cc[k];
                int b = c >> NBBITS;
                int pos = atomicAdd(&myh[b], 1);
                stage[pos] = rr2[k] | ((c & ((1u << NBBITS) - 1)) << 17);
            }
        }
        __syncthreads();
        // bptr: one counter per 64-B line -> no cross-XCD false sharing
        if (tid < NBK_PAD && hcnt[tid])
            gbase[tid] = atomicAdd(&bptr[tid * BSTRIDE], hcnt[tid]);
        __syncthreads();
        // ---- edge-major dense flush: thread i flushes stage[i] ----
        // stage is bucket-sorted; bucket via 9-step binary search in lofs.
        for (int i = tid; i < nE; i += 512) {
            int lob = 0, hib = NBK_PAD;
            #pragma unroll
            for (int it = 0; it < 9; ++it) {      // log2(512)
                int mid = (lob + hib) >> 1;
                if (lofs[mid] <= i) lob = mid; else hib = mid;
            }
            int b = lob;
            ebuf[(size_t)b * SCAP + gbase[b] + (i - lofs[b])] = stage[i];
        }
    } else {
        // ------- gemm path: H1 = bf16(X @ W1) via MFMA 16x16x32 bf16 -------
        unsigned short* Wt = (unsigned short*)smraw;   // [64 cols][64 k] bf16
        // stage W1 transposed+bf16 into LDS
        for (int i = tid; i < 64 * 64; i += 512) {
            int c = i & 63, k = i >> 6;
            Wt[c * 64 + k] = f2b(W[k * 64 + c]);
        }
        __syncthreads();
        int lm = lane & 15, lk = lane >> 4;            // m/n index, k-subgroup
        int gwid = (blockIdx.x - nPart) * NWV + wv;    // global gemm wave id
        int wstride = nGemm * NWV;
        int ntiles = (N + 15) >> 4;
        for (int tile = gwid; tile < ntiles; tile += wstride) {
            int rbase = tile << 4;
            int arow = rbase + lm;
            const float* xr = x + (size_t)(arow < N ? arow : N - 1) * 64;
            bf16x8 afrag[2];
            #pragma unroll
            for (int ks = 0; ks < 2; ++ks) {
                float4 u0 = *(const float4*)(xr + ks * 32 + lk * 8);
                float4 u1 = *(const float4*)(xr + ks * 32 + lk * 8 + 4);
                afrag[ks][0] = (short)f2b(u0.x); afrag[ks][1] = (short)f2b(u0.y);
                afrag[ks][2] = (short)f2b(u0.z); afrag[ks][3] = (short)f2b(u0.w);
                afrag[ks][4] = (short)f2b(u1.x); afrag[ks][5] = (short)f2b(u1.y);
                afrag[ks][6] = (short)f2b(u1.z); afrag[ks][7] = (short)f2b(u1.w);
            }
            f32x4 acc[4] = {{0.f, 0.f, 0.f, 0.f}, {0.f, 0.f, 0.f, 0.f},
                            {0.f, 0.f, 0.f, 0.f}, {0.f, 0.f, 0.f, 0.f}};
            #pragma unroll
            for (int ks = 0; ks < 2; ++ks)
                #pragma unroll
                for (int ct = 0; ct < 4; ++ct) {
                    bf16x8 bf = *(const bf16x8*)(Wt + (ct * 16 + lm) * 64
                                                 + ks * 32 + lk * 8);
                    acc[ct] = __builtin_amdgcn_mfma_f32_16x16x32_bf16(
                        afrag[ks], bf, acc[ct], 0, 0, 0);
                }
            // D: col = ct*16 + (lane&15), row = rbase + (lane>>4)*4 + j
            #pragma unroll
            for (int ct = 0; ct < 4; ++ct)
                #pragma unroll
                for (int j = 0; j < 4; ++j) {
                    int row = rbase + lk * 4 + j;
                    if (row < N)
                        H[(size_t)row * 64 + ct * 16 + lm] = f2b(acc[ct][j]);
                }
        }
    }
}

// per-bucket exact CSR over 256-node buckets: SINGLE pass over ebuf —
// entries loaded once into registers (<=10/thread), hist, 256-entry scan
// -> offs/dinv, DEGREE-SORT perm (64-bin counting sort), scatter from
// registers into LDS stage, srcA dump.
__global__ __launch_bounds__(512, 8) void k_bucket(
        const unsigned* __restrict__ ebuf, const int* __restrict__ bptr,
        int* __restrict__ offs, float* __restrict__ dinv,
        int* __restrict__ srcA, int* __restrict__ perm, int N, int E) {
    __shared__ int hist[256];
    __shared__ int escan[256];
    __shared__ int dhist[64];
    __shared__ int wsum[8];
    __shared__ int loSh;
    __shared__ int stage[SCAP];
    int tid = threadIdx.x, b = blockIdx.x;
    int lane = tid & 63, wid = tid >> 6;
    if (tid < 256) hist[tid] = 0;
    // lo = sum of counts of buckets < b (8-wave reduce over 512 counts)
    int cb = (tid < b) ? bptr[tid * BSTRIDE] : 0;
    #pragma unroll
    for (int off = 32; off > 0; off >>= 1) cb += __shfl_xor(cb, off);
    if (lane == 0) wsum[wid] = cb;
    if (tid == 0 && b == 0) offs[N] = E;
    __syncthreads();
    if (tid == 0) {
        int t = 0;
        #pragma unroll
        for (int q = 0; q < 8; ++q) t += wsum[q];
        loSh = t;
    }
    __syncthreads();
    int lo = loSh;
    int m = bptr[b * BSTRIDE];
    size_t rb = (size_t)b * SCAP;
    // single global pass: load edges into registers (coalesced, 10-deep)
    unsigned ew[RPB];
    #pragma unroll
    for (int k = 0; k < RPB; ++k) {
        int idx = tid + k * 512;
        ew[k] = (idx < m) ? ebuf[rb + idx] : 0xFFFFFFFFu;
    }
    // per-node degree histogram from registers
    #pragma unroll
    for (int k = 0; k < RPB; ++k)
        if (ew[k] != 0xFFFFFFFFu) atomicAdd(&hist[ew[k] >> 17], 1);
    __syncthreads();
    // 256-entry exclusive scan (4 waves shfl + cross-wave sums)
    if (tid < 256) {
        int v = hist[tid], ss = v;
        #pragma unroll
        for (int off = 1; off < 64; off <<= 1) {
            int t2 = __shfl(ss, lane - off);
            if (lane >= off) ss += t2;
        }
        if (lane == 63) wsum[wid] = ss;
        escan[tid] = ss - v;
    } else if (tid < 320) {
        dhist[tid - 256] = 0;           // zero degree-count bins
    }
    __syncthreads();
    if (tid < 256) {
        int w4 = tid >> 6, add = 0;
        #pragma unroll
        for (int q = 0; q < 4; ++q)
            if (q < w4) add += wsum[q];
        int ex = escan[tid] + add;
        escan[tid] = ex;
        int g = (b << NBBITS) + tid;
        if (g < N) {
            offs[g] = lo + ex;
            dinv[g] = rsqrtf((float)(hist[tid] + 1));   // +1 self-loop
        }
        atomicAdd(&dhist[min(hist[tid], 63)], 1);       // degree counts
    }
    __syncthreads();
    // exclusive scan of the 64 degree bins (wave 0)
    if (tid < 64) {
        int v = dhist[tid], ss = v;
        #pragma unroll
        for (int off = 1; off < 64; off <<= 1) {
            int t2 = __shfl(ss, lane - off);
            if (lane >= off) ss += t2;
        }
        dhist[tid] = ss - v;            // exclusive base per degree bin
    }
    __syncthreads();
    // rank = base + intra-bin cursor -> perm slot (bijective over 256)
    if (tid < 256) {
        int d = min(hist[tid], 63);
        int rank = atomicAdd(&dhist[d], 1);
        int g = (b << NBBITS) + tid;
        perm[(b << NBBITS) + rank] = (g < N) ? g : -1;
    }
    __syncthreads();
    // scatter from registers into LDS stage sorted by local node
    #pragma unroll
    for (int k = 0; k < RPB; ++k) {
        if (ew[k] != 0xFFFFFFFFu) {
            unsigned w = ew[k];
            int lc = w >> 17;
            int src = (int)(w & 0x1FFFFu);
            int sl = escan[lc] + atomicSub(&hist[lc], 1) - 1;
            if (sl < SCAP) stage[sl] = src;
            else srcA[lo + sl] = src;   // statistically-cold overflow
        }
    }
    __syncthreads();
    int mm = min(m, SCAP);
    for (int i = tid; i < mm; i += 512) srcA[lo + i] = stage[i];
}

// Layer-1 aggregation: 8 nodes per wave (8-lane groups), nodes assigned via
// the DEGREE-SORTED perm so each group's 8 nodes have near-equal degree
// (cm ~ cnt: no masked gather iterations). Lane s of group g owns features
// 8s..8s+7 of node perm[wid*8+g]: private accumulation, no parity fold.
// Per j0-block: 8 independent uint4 gathers issued before any consume
// (8-deep MLP), next chunk's (src,w) prefetched under the gathers+FMAs.
// Fused with relu, bias, and the 64->2 GEMM of layer 2. Writes Z=[N,2].
__global__ void k_agg1(const unsigned short* __restrict__ H1,
                       const int* __restrict__ srcA,
                       const float* __restrict__ dinv, const int* __restrict__ offs,
                       const int* __restrict__ perm,
                       const float* __restrict__ b1, const float* __restrict__ W2,
                       float* __restrict__ Z, int N, int nSlots) {
    int wid = (blockIdx.x * blockDim.x + threadIdx.x) >> 6;
    int lane = threadIdx.x & 63;
    int g = lane >> 3, s = lane & 7;
    int slot = wid * 8 + g;
    int n = (slot < nSlots) ? perm[slot] : -1;
    bool nvalid = (n >= 0);
    int nn = nvalid ? n : 0;
    float dn = dinv[nn];
    int base = offs[nn];
    int cnt = nvalid ? (offs[nn + 1] - base) : 0;
    // wave-uniform loop bound: max degree over the 8 groups (sorted: ~equal)
    int cm = cnt;
    #pragma unroll
    for (int off = 8; off <= 32; off <<= 1) cm = max(cm, __shfl_xor(cm, off));
    const uint4* H4 = (const uint4*)H1;   // row r = H4[r*8 + s]
    // hoist independent loads: self-loop row, bias, W2 columns
    uint4 rs = H4[(size_t)nn * 8 + s];
    float4 b1a = *(const float4*)(b1 + s * 8);
    float4 b1b = *(const float4*)(b1 + s * 8 + 4);
    const float4* w2p = (const float4*)(W2 + s * 16);
    float4 q0 = w2p[0], q1 = w2p[1], q2 = w2p[2], q3 = w2p[3];
    float a[8];
    #pragma unroll
    for (int k = 0; k < 8; ++k) a[k] = 0.f;
    int gb = g << 3;
    // prologue: load first chunk's (src, w)
    int sv = 0; float wl = 0.f;
    if (s < cnt) { sv = srcA[base + s]; wl = dinv[sv]; }
    for (int j0 = 0; j0 < cm; j0 += 8) {
        // prefetch next chunk's (src, w) — drains under gathers + FMAs below
        int svn = 0; float wln = 0.f;
        int jn = j0 + 8;
        if (jn + s < cnt) { svn = srcA[base + jn + s]; wln = dinv[svn]; }
        int   s0 = __shfl(sv, gb + 0), s1 = __shfl(sv, gb + 1);
        int   s2 = __shfl(sv, gb + 2), s3 = __shfl(sv, gb + 3);
        int   s4 = __shfl(sv, gb + 4), s5 = __shfl(sv, gb + 5);
        int   s6 = __shfl(sv, gb + 6), s7 = __shfl(sv, gb + 7);
        float w0 = __shfl(wl, gb + 0), w1 = __shfl(wl, gb + 1);
        float w2 = __shfl(wl, gb + 2), w3 = __shfl(wl, gb + 3);
        float w4 = __shfl(wl, gb + 4), w5 = __shfl(wl, gb + 5);
        float w6 = __shfl(wl, gb + 6), w7 = __shfl(wl, gb + 7);
        uint4 r0 = H4[(size_t)s0 * 8 + s];
        uint4 r1 = H4[(size_t)s1 * 8 + s];
        uint4 r2 = H4[(size_t)s2 * 8 + s];
        uint4 r3 = H4[(size_t)s3 * 8 + s];
        uint4 r4 = H4[(size_t)s4 * 8 + s];
        uint4 r5 = H4[(size_t)s5 * 8 + s];
        uint4 r6 = H4[(size_t)s6 * 8 + s];
        uint4 r7 = H4[(size_t)s7 * 8 + s];
        acc8(a, r0, w0); acc8(a, r1, w1); acc8(a, r2, w2); acc8(a, r3, w3);
        acc8(a, r4, w4); acc8(a, r5, w5); acc8(a, r6, w6); acc8(a, r7, w7);
        sv = svn; wl = wln;
    }
    // self-loop term
    acc8(a, rs, dn);
    float h0 = fmaxf(dn * a[0] + b1a.x, 0.f);
    float h1 = fmaxf(dn * a[1] + b1a.y, 0.f);
    float h2 = fmaxf(dn * a[2] + b1a.z, 0.f);
    float h3 = fmaxf(dn * a[3] + b1a.w, 0.f);
    float h4 = fmaxf(dn * a[4] + b1b.x, 0.f);
    float h5 = fmaxf(dn * a[5] + b1b.y, 0.f);
    float h6 = fmaxf(dn * a[6] + b1b.z, 0.f);
    float h7 = fmaxf(dn * a[7] + b1b.w, 0.f);
    float p0 = h0 * q0.x + h1 * q0.z + h2 * q1.x + h3 * q1.z
             + h4 * q2.x + h5 * q2.z + h6 * q3.x + h7 * q3.z;
    float p1 = h0 * q0.y + h1 * q0.w + h2 * q1.y + h3 * q1.w
             + h4 * q2.y + h5 * q2.w + h6 * q3.y + h7 * q3.w;
    // sum the 8 feature-octs within this group (xor stays inside the group)
    #pragma unroll
    for (int off = 1; off < 8; off <<= 1) {
        p0 += __shfl_xor(p0, off);
        p1 += __shfl_xor(p1, off);
    }
    if (s == 0 && nvalid) { Z[n * 2 + 0] = p0; Z[n * 2 + 1] = p1; }
}

// Layer-2 aggregation over Z=[N,2]: 4 nodes per wave (avg degree 16 -> full
// lane utilization), 16 lanes over neighbors per node.
__global__ void k_agg2(const float* __restrict__ Z, const int* __restrict__ srcA,
                       const float* __restrict__ dinv, const int* __restrict__ offs,
                       const float* __restrict__ b2, float* __restrict__ out, int N) {
    int t = blockIdx.x * blockDim.x + threadIdx.x;
    int lane = threadIdx.x & 63;
    int n = (t >> 6) * 4 + (lane >> 4);
    int sl = lane & 15;
    if (n >= N) return;                 // uniform per 16-lane group
    int base = offs[n];
    int cnt = offs[n + 1] - base;
    float a0 = 0.f, a1 = 0.f;
    const float2* Z2 = (const float2*)Z;
    for (int i = sl; i < cnt; i += 16) {
        int src = srcA[base + i];
        float w = dinv[src];
        float2 zv = Z2[src];
        a0 += w * zv.x;
        a1 += w * zv.y;
    }
    #pragma unroll
    for (int off = 8; off > 0; off >>= 1) {
        a0 += __shfl_xor(a0, off);
        a1 += __shfl_xor(a1, off);
    }
    if (sl == 0) {
        float dn = dinv[n];
        float2 zs = Z2[n];
        out[n * 2 + 0] = dn * (a0 + dn * zs.x) + b2[0];
        out[n * 2 + 1] = dn * (a1 + dn * zs.y) + b2[1];
    }
}

extern "C" void kernel_launch(void* const* d_in, const int* in_sizes, int n_in,
                              void* d_out, int out_size, void* d_ws, size_t ws_size,
                              hipStream_t stream) {
    const float* x  = (const float*)d_in[0];
    const int*   ep = (const int*)d_in[1];
    const float* W1 = (const float*)d_in[2];
    const float* b1 = (const float*)d_in[3];
    const float* W2 = (const float*)d_in[4];
    const float* b2 = (const float*)d_in[5];
    float* out = (float*)d_out;

    const int N = in_sizes[0] / D_IN;   // 100000
    const int E = in_sizes[1] / 2;      // 1600000

    char* ws = (char*)d_ws;
    size_t o = 0;
    auto alloc = [&](size_t bytes) {
        size_t r = o;
        o = (o + bytes + 255) & ~(size_t)255;
        return r;
    };
    const int nbk = (N + (1 << NBBITS) - 1) >> NBBITS;   // 391
    const int nSlots = nbk << NBBITS;                    // 100096
    int*            bptr  = (int*)           (ws + alloc((size_t)NBK_PAD * BSTRIDE * 4));
    float*          dinv  = (float*)         (ws + alloc((size_t)N * 4));
    int*            offs  = (int*)           (ws + alloc((size_t)(N + 1) * 4));
    int*            perm  = (int*)           (ws + alloc((size_t)nSlots * 4));
    unsigned*       ebuf  = (unsigned*)      (ws + alloc((size_t)NBK_PAD * SCAP * 4));
    int*            srcA  = (int*)           (ws + alloc((size_t)E * 4));
    unsigned short* H1    = (unsigned short*)(ws + alloc((size_t)N * 64 * 2));
    float*          Z     = (float*)         (ws + alloc((size_t)N * 2 * 4));

    const int nPart = (E + PCH - 1) / PCH;               // 391
    int nGemm = 1024 - nPart;                            // 4 blocks/CU co-resident
    if (nGemm < 64) nGemm = 64;

    (void)hipMemsetAsync(bptr, 0, (size_t)NBK_PAD * BSTRIDE * sizeof(int), stream);
    k_part_gemm<<<nPart + nGemm, 512, 0, stream>>>(ep, bptr, ebuf, x, W1, H1,
                                                   E, N, nPart, nGemm);
    k_bucket<<<nbk, 512, 0, stream>>>(ebuf, bptr, offs, dinv, srcA, perm, N, E);
    // 8 perm slots per wave -> nSlots/8 waves -> /4 waves per block
    int nwav = (nSlots + 7) / 8;
    k_agg1<<<(nwav + 3) / 4, 256, 0, stream>>>(H1, srcA, dinv, offs, perm,
                                               b1, W2, Z, N, nSlots);
    k_agg2<<<(N + 15) / 16, 256, 0, stream>>>(Z, srcA, dinv, offs, b2, out, N);
}

// Round 15
// 88.608 us; speedup vs baseline: 1.0868x; 1.0868x over previous
//
#include <hip/hip_runtime.h>

// GCN 2-layer: out = Ahat * relu(Ahat*(X W1)+b1) * W2 + b2
// Ahat = D^-1/2 (A+I) D^-1/2, pull-based CSR aggregation.
// R22 = R20 verbatim (session best, 88.6us). R21's degree-sorted perm
//     regressed (+7.7us): index-adjacent node grouping gives contiguous
//     srcA segments + sequential Z writes; perm indirection scattered both,
//     costing more than the ~30% masked-iteration saving. Measured-final
//     structure: fat part+gemm kernel (MFMA gemm riding under the edge
//     partition), 512-bucket counting sort with per-wave split histograms
//     and edge-major binary-search flush, single-pass k_bucket CSR,
//     8-deep-MLP gather agg1 with (src,w) prefetch, 16-lane-group agg2.

#define D_IN 64
#define NBBITS 8           // 256 nodes per bucket
#define NBK_PAD 512        // padded bucket count (N=100K -> 391 real)
#define BSTRIDE 16         // bptr stride: one counter per 64-B cache line
#define PCH 4096           // edges per part block
#define NWV 8              // waves per part block
#define SCAP 5120          // per-bucket edge capacity (mean ~4092, sd ~64)
#define RPB 10             // k_bucket register entries per thread (512*10=5120)

typedef __attribute__((ext_vector_type(8))) short bf16x8;
typedef __attribute__((ext_vector_type(4))) float f32x4;

// ---- bf16 helpers (RN-even) ----
__device__ __forceinline__ float b2f(unsigned short u) {
    unsigned v = ((unsigned)u) << 16;
    float f;
    __builtin_memcpy(&f, &v, 4);
    return f;
}
__device__ __forceinline__ unsigned short f2b(float f) {
    unsigned u;
    __builtin_memcpy(&u, &f, 4);
    u += 0x7FFFu + ((u >> 16) & 1u);
    return (unsigned short)(u >> 16);
}

// accumulate 8 bf16 features (one uint4) scaled by wgt into a[0..7]
__device__ __forceinline__ void acc8(float* a, uint4 rv, float wgt) {
    a[0] = fmaf(wgt, b2f((unsigned short)(rv.x & 0xFFFFu)), a[0]);
    a[1] = fmaf(wgt, b2f((unsigned short)(rv.x >> 16)), a[1]);
    a[2] = fmaf(wgt, b2f((unsigned short)(rv.y & 0xFFFFu)), a[2]);
    a[3] = fmaf(wgt, b2f((unsigned short)(rv.y >> 16)), a[3]);
    a[4] = fmaf(wgt, b2f((unsigned short)(rv.z & 0xFFFFu)), a[4]);
    a[5] = fmaf(wgt, b2f((unsigned short)(rv.z >> 16)), a[5]);
    a[6] = fmaf(wgt, b2f((unsigned short)(rv.w & 0xFFFFu)), a[6]);
    a[7] = fmaf(wgt, b2f((unsigned short)(rv.w >> 16)), a[7]);
}

// Fat kernel: blocks [0, nPart) partition 4096-edge chunks (counting sort
// with per-wave split histograms, 512 buckets, edge-major dense flush);
// blocks [nPart, grid) do H1 = bf16(X @ W1) via MFMA 16x16x32 bf16.
__global__ __launch_bounds__(512, 8) void k_part_gemm(
        const int* __restrict__ ep, int* __restrict__ bptr,
        unsigned* __restrict__ ebuf,
        const float* __restrict__ x, const float* __restrict__ W,
        unsigned short* __restrict__ H, int E, int N, int nPart, int nGemm) {
    __shared__ __align__(16) char smraw[39040];
    int tid = threadIdx.x;
    int lane = tid & 63;
    int wv = tid >> 6;                            // wave 0..7

    if (blockIdx.x < nPart) {
        // ---------------- partition path ----------------
        int* whist = (int*)smraw;                 // [8][512] per-wave hists
        int* lofs  = whist + NWV * NBK_PAD;       // [512]
        int* hcnt  = lofs + NBK_PAD;              // [512]
        int* gbase = hcnt + NBK_PAD;              // [512]
        int* fsh   = gbase + NBK_PAD;             // [16]: flag + 8 wave sums
        unsigned* stage = (unsigned*)(fsh + 16);  // [PCH]

        for (int i = tid; i < NWV * NBK_PAD; i += 512) whist[i] = 0;
        // per-block dtype detect (8 KB redundant read, L2-shared)
        if (tid < 64) {
            int bad = 0;
            for (int i = tid; i < 1024; i += 64)
                if (ep[2 * i + 1] != 0) bad = 1;
            unsigned long long m = __ballot(bad);
            if (tid == 0) fsh[0] = (m == 0ull) ? 1 : 0;   // 1 => int64
        }
        __syncthreads();
        int f = fsh[0];
        long base = (long)blockIdx.x * PCH;
        long rem64 = (long)E - base;
        int nE = rem64 > PCH ? PCH : (int)rem64;
        int j0 = tid * 8;                 // this thread's 8 local edges
        int nv = nE - j0;
        nv = nv < 0 ? 0 : (nv > 8 ? 8 : nv);
        unsigned cc[8], rr2[8];
        #pragma unroll
        for (int k = 0; k < 8; ++k) { cc[k] = 0; rr2[k] = 0; }
        bool fullv = (nv == 8);
        const uint4* p4 = (const uint4*)ep;
        // ---- load 8 cols into registers (coalesced uint4 when aligned) ----
        if (f) {
            if (fullv && ((E & 1) == 0)) {
                size_t cb = ((size_t)E + (size_t)base + j0) >> 1;   // uint4 idx
                uint4 a0 = p4[cb + 0], a1 = p4[cb + 1];
                uint4 a2 = p4[cb + 2], a3 = p4[cb + 3];
                cc[0] = a0.x; cc[1] = a0.z; cc[2] = a1.x; cc[3] = a1.z;
                cc[4] = a2.x; cc[5] = a2.z; cc[6] = a3.x; cc[7] = a3.z;
            } else {
                for (int k = 0; k < 8; ++k)
                    if (k < nv) cc[k] = (unsigned)ep[2 * ((size_t)E + base + j0 + k)];
            }
        } else {
            if (fullv && ((E & 3) == 0)) {
                size_t cb = ((size_t)E + (size_t)base + j0) >> 2;
                uint4 a0 = p4[cb + 0], a1 = p4[cb + 1];
                cc[0] = a0.x; cc[1] = a0.y; cc[2] = a0.z; cc[3] = a0.w;
                cc[4] = a1.x; cc[5] = a1.y; cc[6] = a1.z; cc[7] = a1.w;
            } else {
                for (int k = 0; k < 8; ++k)
                    if (k < nv) cc[k] = (unsigned)ep[(size_t)E + base + j0 + k];
            }
        }
        // ---- row loads issued BEFORE hist: cols+rows in flight together ----
        if (f) {
            if (fullv && ((E & 1) == 0)) {
                size_t rbb = ((size_t)base + j0) >> 1;
                uint4 b0 = p4[rbb + 0], b1 = p4[rbb + 1];
                uint4 b2 = p4[rbb + 2], b3 = p4[rbb + 3];
                rr2[0] = b0.x; rr2[1] = b0.z; rr2[2] = b1.x; rr2[3] = b1.z;
                rr2[4] = b2.x; rr2[5] = b2.z; rr2[6] = b3.x; rr2[7] = b3.z;
            } else {
                for (int k = 0; k < 8; ++k)
                    if (k < nv) rr2[k] = (unsigned)ep[2 * ((size_t)base + j0 + k)];
            }
        } else {
            if (fullv && ((E & 3) == 0)) {
                size_t rbb = ((size_t)base + j0) >> 2;
                uint4 b0 = p4[rbb + 0], b1 = p4[rbb + 1];
                rr2[0] = b0.x; rr2[1] = b0.y; rr2[2] = b0.z; rr2[3] = b0.w;
                rr2[4] = b1.x; rr2[5] = b1.y; rr2[6] = b1.z; rr2[7] = b1.w;
            } else {
                for (int k = 0; k < 8; ++k)
                    if (k < nv) rr2[k] = (unsigned)ep[(size_t)base + j0 + k];
            }
        }
        // per-wave histogram (collisions only intra-wave)
        int* myh = whist + wv * NBK_PAD;
        #pragma unroll
        for (int k = 0; k < 8; ++k)
            if (k < nv) atomicAdd(&myh[cc[k] >> NBBITS], 1);
        __syncthreads();
        // ---- combine per-wave hists + 512-entry exclusive scan ----
        if (tid < NBK_PAD) {
            int run = 0;
            #pragma unroll
            for (int w = 0; w < NWV; ++w) {
                int v = whist[w * NBK_PAD + tid];
                whist[w * NBK_PAD + tid] = run;   // per-wave prefix in bucket
                run += v;
            }
            hcnt[tid] = run;
            int s = run;
            #pragma unroll
            for (int off = 1; off < 64; off <<= 1) {
                int t2 = __shfl(s, lane - off);
                if (lane >= off) s += t2;
            }
            if (lane == 63) fsh[1 + (tid >> 6)] = s;
            lofs[tid] = s - run;
        }
        __syncthreads();
        if (tid < NBK_PAD) {
            int w8 = tid >> 6, add = 0;
            #pragma unroll
            for (int q = 0; q < NWV; ++q)
                if (q < w8) add += fsh[1 + q];
            lofs[tid] += add;
        }
        __syncthreads();
        // fold bucket base into per-wave cursors
        for (int i = tid; i < NWV * NBK_PAD; i += 512)
            whist[i] += lofs[i & (NBK_PAD - 1)];
        __syncthreads();
        // ---- scatter into LDS stage (cursor atomics intra-wave only) ----
        #pragma unroll
        for (int k = 0; k < 8; ++k) {
            if (k < nv) {
                unsigned c = cc[k];
                int b = c >> NBBITS;
                int pos = atomicAdd(&myh[b], 1);
                stage[pos] = rr2[k] | ((c & ((1u << NBBITS) - 1)) << 17);
            }
        }
        __syncthreads();
        // bptr: one counter per 64-B line -> no cross-XCD false sharing
        if (tid < NBK_PAD && hcnt[tid])
            gbase[tid] = atomicAdd(&bptr[tid * BSTRIDE], hcnt[tid]);
        __syncthreads();
        // ---- edge-major dense flush: thread i flushes stage[i] ----
        // stage is bucket-sorted; bucket via 9-step binary search in lofs.
        for (int i = tid; i < nE; i += 512) {
            int lob = 0, hib = NBK_PAD;
            #pragma unroll
            for (int it = 0; it < 9; ++it) {      // log2(512)
                int mid = (lob + hib) >> 1;
                if (lofs[mid] <= i) lob = mid; else hib = mid;
            }
            int b = lob;
            ebuf[(size_t)b * SCAP + gbase[b] + (i - lofs[b])] = stage[i];
        }
    } else {
        // ------- gemm path: H1 = bf16(X @ W1) via MFMA 16x16x32 bf16 -------
        unsigned short* Wt = (unsigned short*)smraw;   // [64 cols][64 k] bf16
        // stage W1 transposed+bf16 into LDS
        for (int i = tid; i < 64 * 64; i += 512) {
            int c = i & 63, k = i >> 6;
            Wt[c * 64 + k] = f2b(W[k * 64 + c]);
        }
        __syncthreads();
        int lm = lane & 15, lk = lane >> 4;            // m/n index, k-subgroup
        int gwid = (blockIdx.x - nPart) * NWV + wv;    // global gemm wave id
        int wstride = nGemm * NWV;
        int ntiles = (N + 15) >> 4;
        for (int tile = gwid; tile < ntiles; tile += wstride) {
            int rbase = tile << 4;
            int arow = rbase + lm;
            const float* xr = x + (size_t)(arow < N ? arow : N - 1) * 64;
            bf16x8 afrag[2];
            #pragma unroll
            for (int ks = 0; ks < 2; ++ks) {
                float4 u0 = *(const float4*)(xr + ks * 32 + lk * 8);
                float4 u1 = *(const float4*)(xr + ks * 32 + lk * 8 + 4);
                afrag[ks][0] = (short)f2b(u0.x); afrag[ks][1] = (short)f2b(u0.y);
                afrag[ks][2] = (short)f2b(u0.z); afrag[ks][3] = (short)f2b(u0.w);
                afrag[ks][4] = (short)f2b(u1.x); afrag[ks][5] = (short)f2b(u1.y);
                afrag[ks][6] = (short)f2b(u1.z); afrag[ks][7] = (short)f2b(u1.w);
            }
            f32x4 acc[4] = {{0.f, 0.f, 0.f, 0.f}, {0.f, 0.f, 0.f, 0.f},
                            {0.f, 0.f, 0.f, 0.f}, {0.f, 0.f, 0.f, 0.f}};
            #pragma unroll
            for (int ks = 0; ks < 2; ++ks)
                #pragma unroll
                for (int ct = 0; ct < 4; ++ct) {
                    bf16x8 bf = *(const bf16x8*)(Wt + (ct * 16 + lm) * 64
                                                 + ks * 32 + lk * 8);
                    acc[ct] = __builtin_amdgcn_mfma_f32_16x16x32_bf16(
                        afrag[ks], bf, acc[ct], 0, 0, 0);
                }
            // D: col = ct*16 + (lane&15), row = rbase + (lane>>4)*4 + j
            #pragma unroll
            for (int ct = 0; ct < 4; ++ct)
                #pragma unroll
                for (int j = 0; j < 4; ++j) {
                    int row = rbase + lk * 4 + j;
                    if (row < N)
                        H[(size_t)row * 64 + ct * 16 + lm] = f2b(acc[ct][j]);
                }
        }
    }
}

// per-bucket exact CSR over 256-node buckets: SINGLE pass over ebuf —
// entries loaded once into registers (<=10/thread), hist, 256-entry scan
// -> offs/dinv, scatter from registers into LDS stage, srcA dump.
__global__ __launch_bounds__(512, 8) void k_bucket(
        const unsigned* __restrict__ ebuf, const int* __restrict__ bptr,
        int* __restrict__ offs, float* __restrict__ dinv,
        int* __restrict__ srcA, int N, int E) {
    __shared__ int hist[256];
    __shared__ int escan[256];
    __shared__ int wsum[8];
    __shared__ int loSh;
    __shared__ int stage[SCAP];
    int tid = threadIdx.x, b = blockIdx.x;
    int lane = tid & 63, wid = tid >> 6;
    if (tid < 256) hist[tid] = 0;
    // lo = sum of counts of buckets < b (8-wave reduce over 512 counts)
    int cb = (tid < b) ? bptr[tid * BSTRIDE] : 0;
    #pragma unroll
    for (int off = 32; off > 0; off >>= 1) cb += __shfl_xor(cb, off);
    if (lane == 0) wsum[wid] = cb;
    if (tid == 0 && b == 0) offs[N] = E;
    __syncthreads();
    if (tid == 0) {
        int t = 0;
        #pragma unroll
        for (int q = 0; q < 8; ++q) t += wsum[q];
        loSh = t;
    }
    __syncthreads();
    int lo = loSh;
    int m = bptr[b * BSTRIDE];
    size_t rb = (size_t)b * SCAP;
    // single global pass: load edges into registers (coalesced, 10-deep)
    unsigned ew[RPB];
    #pragma unroll
    for (int k = 0; k < RPB; ++k) {
        int idx = tid + k * 512;
        ew[k] = (idx < m) ? ebuf[rb + idx] : 0xFFFFFFFFu;
    }
    // per-node degree histogram from registers
    #pragma unroll
    for (int k = 0; k < RPB; ++k)
        if (ew[k] != 0xFFFFFFFFu) atomicAdd(&hist[ew[k] >> 17], 1);
    __syncthreads();
    // 256-entry exclusive scan (4 waves shfl + cross-wave sums)
    if (tid < 256) {
        int v = hist[tid], ss = v;
        #pragma unroll
        for (int off = 1; off < 64; off <<= 1) {
            int t2 = __shfl(ss, lane - off);
            if (lane >= off) ss += t2;
        }
        if (lane == 63) wsum[wid] = ss;
        escan[tid] = ss - v;
    }
    __syncthreads();
    if (tid < 256) {
        int w4 = tid >> 6, add = 0;
        #pragma unroll
        for (int q = 0; q < 4; ++q)
            if (q < w4) add += wsum[q];
        int ex = escan[tid] + add;
        escan[tid] = ex;
        int g = (b << NBBITS) + tid;
        if (g < N) {
            offs[g] = lo + ex;
            dinv[g] = rsqrtf((float)(hist[tid] + 1));   // +1 self-loop
        }
    }
    __syncthreads();
    // scatter from registers into LDS stage sorted by local node
    #pragma unroll
    for (int k = 0; k < RPB; ++k) {
        if (ew[k] != 0xFFFFFFFFu) {
            unsigned w = ew[k];
            int lc = w >> 17;
            int src = (int)(w & 0x1FFFFu);
            int sl = escan[lc] + atomicSub(&hist[lc], 1) - 1;
            if (sl < SCAP) stage[sl] = src;
            else srcA[lo + sl] = src;   // statistically-cold overflow
        }
    }
    __syncthreads();
    int mm = min(m, SCAP);
    for (int i = tid; i < mm; i += 512) srcA[lo + i] = stage[i];
}

// Layer-1 aggregation: 8 nodes per wave (8-lane groups). Lane s of group g
// owns features 8s..8s+7 of node wid*8+g: private accumulation, no parity
// fold. Per j0-block: 8 independent uint4 gathers issued before any consume
// (8-deep MLP, below the spill cliff), with the NEXT block's (src,w) index
// loads prefetched during the current gather+FMA phase. Fused with relu,
// bias, and the 64->2 GEMM of layer 2. Writes Z=[N,2].
__global__ void k_agg1(const unsigned short* __restrict__ H1,
                       const int* __restrict__ srcA,
                       const float* __restrict__ dinv, const int* __restrict__ offs,
                       const float* __restrict__ b1, const float* __restrict__ W2,
                       float* __restrict__ Z, int N) {
    int wid = (blockIdx.x * blockDim.x + threadIdx.x) >> 6;
    int lane = threadIdx.x & 63;
    int g = lane >> 3, s = lane & 7;
    int n = wid * 8 + g;
    bool nvalid = (n < N);
    int nn = nvalid ? n : 0;
    float dn = dinv[nn];
    int base = offs[nn];
    int cnt = nvalid ? (offs[nn + 1] - base) : 0;
    // wave-uniform loop bound: max degree over the 8 groups
    int cm = cnt;
    #pragma unroll
    for (int off = 8; off <= 32; off <<= 1) cm = max(cm, __shfl_xor(cm, off));
    const uint4* H4 = (const uint4*)H1;   // row r = H4[r*8 + s]
    // hoist independent loads: self-loop row, bias, W2 columns
    uint4 rs = H4[(size_t)nn * 8 + s];
    float4 b1a = *(const float4*)(b1 + s * 8);
    float4 b1b = *(const float4*)(b1 + s * 8 + 4);
    const float4* w2p = (const float4*)(W2 + s * 16);
    float4 q0 = w2p[0], q1 = w2p[1], q2 = w2p[2], q3 = w2p[3];
    float a[8];
    #pragma unroll
    for (int k = 0; k < 8; ++k) a[k] = 0.f;
    int gb = g << 3;
    // prologue: load first chunk's (src, w)
    int sv = 0; float wl = 0.f;
    if (s < cnt) { sv = srcA[base + s]; wl = dinv[sv]; }
    for (int j0 = 0; j0 < cm; j0 += 8) {
        // prefetch next chunk's (src, w) — drains under gathers + FMAs below
        int svn = 0; float wln = 0.f;
        int jn = j0 + 8;
        if (jn + s < cnt) { svn = srcA[base + jn + s]; wln = dinv[svn]; }
        int   s0 = __shfl(sv, gb + 0), s1 = __shfl(sv, gb + 1);
        int   s2 = __shfl(sv, gb + 2), s3 = __shfl(sv, gb + 3);
        int   s4 = __shfl(sv, gb + 4), s5 = __shfl(sv, gb + 5);
        int   s6 = __shfl(sv, gb + 6), s7 = __shfl(sv, gb + 7);
        float w0 = __shfl(wl, gb + 0), w1 = __shfl(wl, gb + 1);
        float w2 = __shfl(wl, gb + 2), w3 = __shfl(wl, gb + 3);
        float w4 = __shfl(wl, gb + 4), w5 = __shfl(wl, gb + 5);
        float w6 = __shfl(wl, gb + 6), w7 = __shfl(wl, gb + 7);
        uint4 r0 = H4[(size_t)s0 * 8 + s];
        uint4 r1 = H4[(size_t)s1 * 8 + s];
        uint4 r2 = H4[(size_t)s2 * 8 + s];
        uint4 r3 = H4[(size_t)s3 * 8 + s];
        uint4 r4 = H4[(size_t)s4 * 8 + s];
        uint4 r5 = H4[(size_t)s5 * 8 + s];
        uint4 r6 = H4[(size_t)s6 * 8 + s];
        uint4 r7 = H4[(size_t)s7 * 8 + s];
        acc8(a, r0, w0); acc8(a, r1, w1); acc8(a, r2, w2); acc8(a, r3, w3);
        acc8(a, r4, w4); acc8(a, r5, w5); acc8(a, r6, w6); acc8(a, r7, w7);
        sv = svn; wl = wln;
    }
    // self-loop term
    acc8(a, rs, dn);
    float h0 = fmaxf(dn * a[0] + b1a.x, 0.f);
    float h1 = fmaxf(dn * a[1] + b1a.y, 0.f);
    float h2 = fmaxf(dn * a[2] + b1a.z, 0.f);
    float h3 = fmaxf(dn * a[3] + b1a.w, 0.f);
    float h4 = fmaxf(dn * a[4] + b1b.x, 0.f);
    float h5 = fmaxf(dn * a[5] + b1b.y, 0.f);
    float h6 = fmaxf(dn * a[6] + b1b.z, 0.f);
    float h7 = fmaxf(dn * a[7] + b1b.w, 0.f);
    float p0 = h0 * q0.x + h1 * q0.z + h2 * q1.x + h3 * q1.z
             + h4 * q2.x + h5 * q2.z + h6 * q3.x + h7 * q3.z;
    float p1 = h0 * q0.y + h1 * q0.w + h2 * q1.y + h3 * q1.w
             + h4 * q2.y + h5 * q2.w + h6 * q3.y + h7 * q3.w;
    // sum the 8 feature-octs within this group (xor stays inside the group)
    #pragma unroll
    for (int off = 1; off < 8; off <<= 1) {
        p0 += __shfl_xor(p0, off);
        p1 += __shfl_xor(p1, off);
    }
    if (s == 0 && nvalid) { Z[n * 2 + 0] = p0; Z[n * 2 + 1] = p1; }
}

// Layer-2 aggregation over Z=[N,2]: 4 nodes per wave (avg degree 16 -> full
// lane utilization), 16 lanes over neighbors per node.
__global__ void k_agg2(const float* __restrict__ Z, const int* __restrict__ srcA,
                       const float* __restrict__ dinv, const int* __restrict__ offs,
                       const float* __restrict__ b2, float* __restrict__ out, int N) {
    int t = blockIdx.x * blockDim.x + threadIdx.x;
    int lane = threadIdx.x & 63;
    int n = (t >> 6) * 4 + (lane >> 4);
    int sl = lane & 15;
    if (n >= N) return;                 // uniform per 16-lane group
    int base = offs[n];
    int cnt = offs[n + 1] - base;
    float a0 = 0.f, a1 = 0.f;
    const float2* Z2 = (const float2*)Z;
    for (int i = sl; i < cnt; i += 16) {
        int src = srcA[base + i];
        float w = dinv[src];
        float2 zv = Z2[src];
        a0 += w * zv.x;
        a1 += w * zv.y;
    }
    #pragma unroll
    for (int off = 8; off > 0; off >>= 1) {
        a0 += __shfl_xor(a0, off);
        a1 += __shfl_xor(a1, off);
    }
    if (sl == 0) {
        float dn = dinv[n];
        float2 zs = Z2[n];
        out[n * 2 + 0] = dn * (a0 + dn * zs.x) + b2[0];
        out[n * 2 + 1] = dn * (a1 + dn * zs.y) + b2[1];
    }
}

extern "C" void kernel_launch(void* const* d_in, const int* in_sizes, int n_in,
                              void* d_out, int out_size, void* d_ws, size_t ws_size,
                              hipStream_t stream) {
    const float* x  = (const float*)d_in[0];
    const int*   ep = (const int*)d_in[1];
    const float* W1 = (const float*)d_in[2];
    const float* b1 = (const float*)d_in[3];
    const float* W2 = (const float*)d_in[4];
    const float* b2 = (const float*)d_in[5];
    float* out = (float*)d_out;

    const int N = in_sizes[0] / D_IN;   // 100000
    const int E = in_sizes[1] / 2;      // 1600000

    char* ws = (char*)d_ws;
    size_t o = 0;
    auto alloc = [&](size_t bytes) {
        size_t r = o;
        o = (o + bytes + 255) & ~(size_t)255;
        return r;
    };
    int*            bptr  = (int*)           (ws + alloc((size_t)NBK_PAD * BSTRIDE * 4));
    float*          dinv  = (float*)         (ws + alloc((size_t)N * 4));
    int*            offs  = (int*)           (ws + alloc((size_t)(N + 1) * 4));
    unsigned*       ebuf  = (unsigned*)      (ws + alloc((size_t)NBK_PAD * SCAP * 4));
    int*            srcA  = (int*)           (ws + alloc((size_t)E * 4));
    unsigned short* H1    = (unsigned short*)(ws + alloc((size_t)N * 64 * 2));
    float*          Z     = (float*)         (ws + alloc((size_t)N * 2 * 4));

    const int nbk = (N + (1 << NBBITS) - 1) >> NBBITS;   // 391
    const int nPart = (E + PCH - 1) / PCH;               // 391
    int nGemm = 1024 - nPart;                            // 4 blocks/CU co-resident
    if (nGemm < 64) nGemm = 64;

    (void)hipMemsetAsync(bptr, 0, (size_t)NBK_PAD * BSTRIDE * sizeof(int), stream);
    k_part_gemm<<<nPart + nGemm, 512, 0, stream>>>(ep, bptr, ebuf, x, W1, H1,
                                                   E, N, nPart, nGemm);
    k_bucket<<<nbk, 512, 0, stream>>>(ebuf, bptr, offs, dinv, srcA, N, E);
    // 8 nodes per wave -> ceil(N/8) waves -> /4 waves per block
    int nwav = (N + 7) / 8;
    k_agg1<<<(nwav + 3) / 4, 256, 0, stream>>>(H1, srcA, dinv, offs, b1, W2, Z, N);
    k_agg2<<<(N + 15) / 16, 256, 0, stream>>>(Z, srcA, dinv, offs, b2, out, N);
}